// Round 13
// baseline (181.594 us; speedup 1.0000x reference)
//
#include <hip/hip_runtime.h>
#include <hip/hip_bf16.h>
#include <cstdint>
#include <cstddef>

typedef __attribute__((ext_vector_type(8))) short short8;
typedef __attribute__((ext_vector_type(4))) float floatx4;
typedef __attribute__((ext_vector_type(16))) float floatx16;

#define B_ 32
#define H_ 8
#define D_ 512
#define DH_ 64
#define SQ_ 512
#define SK_ 512
#define NEG_INF_ -1000000000.0f
#define LOG2E_ 1.4426950408889634f
#define FIXED_MAX_ 24.0f

__device__ __forceinline__ short f2bf(float f) {
  union { float f; uint32_t u; } x; x.f = f;
  uint32_t r = x.u + 0x7FFFu + ((x.u >> 16) & 1u);
  return (short)(r >> 16);
}
__device__ __forceinline__ uint32_t cvt_pk_bf16(float lo, float hi) {
  uint32_t r;
  asm("v_cvt_pk_bf16_f32 %0, %1, %2" : "=v"(r) : "v"(lo), "v"(hi));
  return r;
}
// Swap upper-half lanes of a with lower-half lanes of b (both modified).
__device__ __forceinline__ void plane32_swap(uint32_t& a, uint32_t& b) {
  asm("v_permlane32_swap_b32 %0, %1" : "+v"(a), "+v"(b));
}
__device__ __forceinline__ void gload16(const void* g, void* lds) {
  __builtin_amdgcn_global_load_lds(
      (const __attribute__((address_space(1))) void*)g,
      (__attribute__((address_space(3))) void*)lds, 16, 0, 0);
}
// DCE guards (rule 17): keep values live with zero-cost empty asm.
__device__ __forceinline__ void keepf(float x) { asm volatile("" :: "v"(x)); }
__device__ __forceinline__ void keepu(uint32_t x) { asm volatile("" :: "v"(x)); }
__device__ __forceinline__ void keep8(short8 s) {
  union { short8 v; uint32_t u[4]; } c; c.v = s;
  asm volatile("" :: "v"(c.u[0]), "v"(c.u[1]), "v"(c.u[2]), "v"(c.u[3]));
}
__device__ __forceinline__ void keepx16(const floatx16& f) {
#pragma unroll
  for (int i = 0; i < 16; ++i) asm volatile("" :: "v"(f[i]));
}

// Detect mask element layout: int32 (flag=0) vs byte/bool (flag=1).
__global__ void detect_mask_kernel(const uint8_t* __restrict__ m, int* __restrict__ flag) {
  __shared__ int found;
  if (threadIdx.x == 0) found = 0;
  __syncthreads();
  int any = 0;
  for (int i = threadIdx.x; i < B_ * SK_; i += 256) {
    if ((i & 3) != 0 && m[i] != 0) any = 1;
  }
  if (any) atomicOr(&found, 1);
  __syncthreads();
  if (threadIdx.x == 0) *flag = found;
}

// One fused prep launch (256 thr), role by blockIdx.x (same as r12).
__global__ __launch_bounds__(256) void megaprep_kernel(
    const float* __restrict__ ksrc, const float* __restrict__ vsrc,
    short* __restrict__ kdst, short* __restrict__ vdst,
    const uint8_t* __restrict__ mask8, const int* __restrict__ flag,
    float* __restrict__ kbias,
    const float* __restrict__ m_v, const float* __restrict__ s_v,
    float2* __restrict__ msv,
    const float* __restrict__ W, short* __restrict__ Wb)
{
  __shared__ short t[64][68];
  const int id = blockIdx.x, tid = threadIdx.x;

  if (id < 2048) {
    const int bx = id & 7, h = (id >> 3) & 7, b = id >> 6;
    const int s0 = bx * 64;
    {
      const size_t base = ((size_t)b * D_ + h * DH_ + bx * 8) * (size_t)SK_;
      const float4* vs = reinterpret_cast<const float4*>(vsrc + base);
      short4* vd = reinterpret_cast<short4*>(vdst + base);
      for (int j = 0; j < 4; ++j) {
        const int i = j * 256 + tid;
        const float4 f = vs[i];
        short4 s;
        s.x = f2bf(f.x); s.y = f2bf(f.y); s.z = f2bf(f.z); s.w = f2bf(f.w);
        vd[i] = s;
      }
    }
    const float* sp = ksrc + ((size_t)b * D_ + h * DH_) * (size_t)SK_ + s0;
    const int sg = (tid & 15) * 4;
    int dloc = tid >> 4;
    for (int it = 0; it < 4; ++it, dloc += 16) {
      const float4 f = *reinterpret_cast<const float4*>(sp + (size_t)dloc * SK_ + sg);
      t[sg + 0][dloc] = f2bf(f.x);
      t[sg + 1][dloc] = f2bf(f.y);
      t[sg + 2][dloc] = f2bf(f.z);
      t[sg + 3][dloc] = f2bf(f.w);
    }
    __syncthreads();
    short* dp = kdst + ((size_t)(b * H_ + h) * SQ_ + s0) * 64;
    for (int it = 0; it < 4; ++it) {
      const int c = tid + 256 * it;
      const int ss = c >> 4, pos = (c & 15) * 4;
      *reinterpret_cast<short4*>(dp + (size_t)ss * 64 + pos) =
          *reinterpret_cast<const short4*>(&t[ss][pos]);
    }
  } else if (id < 2080) {
    const int b = id - 2048;
    const int fl = *flag;
    for (int j = 0; j < 2; ++j) {
      const int kk = j * 256 + tid;
      int mv;
      if (fl) mv = mask8[b * SK_ + kk];
      else    mv = reinterpret_cast<const int*>(mask8)[b * SK_ + kk];
      kbias[b * SK_ + kk] = mv ? NEG_INF_ * LOG2E_ : 0.0f;
    }
  } else if (id == 2080) {
    for (int j = 0; j < 2; ++j) {
      const int d = j * 256 + tid;
      const float inv = 1.0f / s_v[d];
      msv[d] = make_float2(inv, m_v[d] * inv);
    }
  } else {
    const int i = (id - 2081) * 256 + tid;
    const float4 f = reinterpret_cast<const float4*>(W)[i];
    short4 s;
    s.x = f2bf(f.x); s.y = f2bf(f.y); s.z = f2bf(f.z); s.w = f2bf(f.w);
    reinterpret_cast<short4*>(Wb)[i] = s;
  }
}

// ABLATION TEMPLATE (r13 measurement round).
// V=0 full (real output). V=1 noStage. V=2 noQK. V=3 noSM. V=4 noPV.
// V>0: no global store; all stubbed values kept live via asm (rule 17).
template<int V>
__global__ __launch_bounds__(512, 4) void attn_t(
    const float* __restrict__ qf32, short* __restrict__ xqT,
    const short* __restrict__ kT, const short* __restrict__ vb,
    const float* __restrict__ gamma, const float* __restrict__ beta,
    const float* __restrict__ m_qk, const float* __restrict__ s_qk,
    const float2* __restrict__ msv, const float* __restrict__ kbias)
{
  __shared__ float bias_s[SK_];
  __shared__ short kbuf[4][4096];
  __shared__ short vbuf[4][4096];

  const int p = blockIdx.x;
  const int grp = (p & 7) * 64 + (p >> 3);
  const int bh = grp >> 1, half = grp & 1;
  const int h = bh & 7, b = bh >> 3;

  const int tid = threadIdx.x, w = tid >> 6, l = tid & 63;
  const int l31 = l & 31, hi = l >> 5;
  const int swz = l31 & 7;

  const float gh = gamma[h], be = beta[h], mq = m_qk[h], sq = s_qk[h];
  const float a2 = gh / (sq * 8.0f) * LOG2E_;
  const float c2 = (be - mq * gh / sq) * LOG2E_ - FIXED_MAX_;

  const int qidx = half * 256 + w * 32 + l31;
  const short* kbase = kT + (size_t)bh * SK_ * 64;
  const short* vbase = vb + ((size_t)b * D_ + h * DH_) * (size_t)SK_;
  const float* qsrc = qf32 + ((size_t)b * D_ + h * DH_) * (size_t)SQ_ + qidx;

  if (tid < 128) {
    floatx4 t = reinterpret_cast<const floatx4*>(kbias + (size_t)b * SK_)[tid];
    t += c2;
    reinterpret_cast<floatx4*>(bias_s)[tid] = t;
  }

  short8 qf[4];
  for (int st = 0; st < 4; ++st) {
    float fv[8];
    for (int j = 0; j < 8; ++j)
      fv[j] = qsrc[(size_t)(st * 16 + hi * 8 + j) * SQ_];
    union { uint32_t u[4]; short8 s; } qk;
    for (int j2 = 0; j2 < 4; ++j2)
      qk.u[j2] = cvt_pk_bf16(fv[2 * j2], fv[2 * j2 + 1]);
    qf[st] = qk.s;
  }

  const int rsub = l >> 3;
  const int c16s = (l & 7) ^ rsub;

  auto stage = [&](short* kdst, short* vdst, int t) {
    const int k0t = t * 64;
    gload16(kbase + (size_t)(k0t + w * 8 + rsub) * 64 + c16s * 8, kdst + w * 512);
    gload16(vbase + (size_t)(w * 8 + rsub) * SK_ + k0t + c16s * 8, vdst + w * 512);
  };

  short *kA = kbuf[0], *kB = kbuf[1], *kC = kbuf[2], *kD = kbuf[3];
  short *vA = vbuf[0], *vB = vbuf[1], *vC = vbuf[2], *vD = vbuf[3];
  stage(kA, vA, 0);
  stage(kB, vB, 1);
  stage(kC, vC, 2);

  floatx16 oacc[2];
  for (int i = 0; i < 16; ++i) { oacc[0][i] = 0.f; oacc[1][i] = 0.f; }
  float lpart = 0.f;

  if (V == 1) asm volatile("s_waitcnt vmcnt(0) lgkmcnt(0)" ::: "memory");
  else        asm volatile("s_waitcnt vmcnt(4) lgkmcnt(0)" ::: "memory");
  __builtin_amdgcn_s_barrier();
  __builtin_amdgcn_sched_barrier(0);

#pragma unroll 1
  for (int it = 0; it < 8; ++it) {
    if (V != 1 && it < 5) stage(kD, vD, it + 3);

    const int k0 = it * 64;
    const short* kl = kA;
    const short* vl = vA;

    // ---- QK phase ----
    floatx16 s0, s1;
    for (int i = 0; i < 16; ++i) { s0[i] = 0.f; s1[i] = 0.f; }
    __builtin_amdgcn_s_setprio(1);
    for (int st = 0; st < 4; ++st) {
      const short8 ka = *reinterpret_cast<const short8*>(
          &kl[(size_t)l31 * 64 + (((st << 1) | hi) ^ swz) * 8]);
      if constexpr (V != 2) s0 = __builtin_amdgcn_mfma_f32_32x32x16_bf16(ka, qf[st], s0, 0, 0, 0);
      else keep8(ka);
    }
    for (int st = 0; st < 4; ++st) {
      const short8 kb = *reinterpret_cast<const short8*>(
          &kl[(size_t)(32 + l31) * 64 + (((st << 1) | hi) ^ swz) * 8]);
      if constexpr (V != 2) s1 = __builtin_amdgcn_mfma_f32_32x32x16_bf16(kb, qf[st], s1, 0, 0, 0);
      else keep8(kb);
    }
    __builtin_amdgcn_s_setprio(0);

    // ---- softmax phase ----
    float p2[32];
    if constexpr (V != 3) {
      for (int sub = 0; sub < 2; ++sub)
        for (int gg = 0; gg < 4; ++gg) {
          const floatx4 bv = *reinterpret_cast<const floatx4*>(
              &bias_s[k0 + sub * 32 + gg * 8 + hi * 4]);
          for (int r = 0; r < 4; ++r) {
            const float sc = sub ? s1[gg * 4 + r] : s0[gg * 4 + r];
            p2[sub * 16 + gg * 4 + r] =
                __builtin_amdgcn_exp2f(__builtin_fmaf(sc, a2, bv[r]));
          }
        }
      float a16[16];
      for (int i = 0; i < 16; ++i) a16[i] = p2[i] + p2[i + 16];
      float a8[8];
      for (int i = 0; i < 8; ++i) a8[i] = a16[i] + a16[i + 8];
      lpart += ((a8[0] + a8[4]) + (a8[1] + a8[5])) + ((a8[2] + a8[6]) + (a8[3] + a8[7]));
    } else {
      for (int i = 0; i < 16; ++i) { p2[i] = s0[i]; p2[16 + i] = s1[i]; }
      lpart += s0[0];
    }

    uint32_t Wd[16];
    for (int j = 0; j < 16; ++j) Wd[j] = cvt_pk_bf16(p2[2 * j], p2[2 * j + 1]);

    // ---- PV phase ----
    __builtin_amdgcn_s_setprio(1);
    for (int kc = 0; kc < 4; ++kc) {
      const int base = (kc >> 1) * 8 + (kc & 1) * 4;
      const short8 va0 = *reinterpret_cast<const short8*>(
          &vl[(size_t)l31 * 64 + (((kc << 1) | hi) ^ swz) * 8]);
      const short8 va1 = *reinterpret_cast<const short8*>(
          &vl[(size_t)(32 + l31) * 64 + (((kc << 1) | hi) ^ swz) * 8]);
      if constexpr (V != 4) {
        uint32_t x0 = Wd[base + 0], x1 = Wd[base + 1];
        uint32_t y0 = Wd[base + 2], y1 = Wd[base + 3];
        plane32_swap(x0, y0);
        plane32_swap(x1, y1);
        union { uint32_t u[4]; short8 s; } pk;
        pk.u[0] = x0; pk.u[1] = x1; pk.u[2] = y0; pk.u[3] = y1;
        const short8 pb = pk.s;
        oacc[0] = __builtin_amdgcn_mfma_f32_32x32x16_bf16(va0, pb, oacc[0], 0, 0, 0);
        oacc[1] = __builtin_amdgcn_mfma_f32_32x32x16_bf16(va1, pb, oacc[1], 0, 0, 0);
      } else {
        keepu(Wd[base + 0]); keepu(Wd[base + 1]);
        keepu(Wd[base + 2]); keepu(Wd[base + 3]);
        keep8(va0); keep8(va1);
      }
    }
    __builtin_amdgcn_s_setprio(0);

    if (it < 7) {
      if (V != 1) {
        if (it < 5)       asm volatile("s_waitcnt vmcnt(4)" ::: "memory");
        else if (it == 5) asm volatile("s_waitcnt vmcnt(2)" ::: "memory");
        else              asm volatile("s_waitcnt vmcnt(0)" ::: "memory");
      }
      __builtin_amdgcn_s_barrier();
      __builtin_amdgcn_sched_barrier(0);
    }

    short* tk = kA; kA = kB; kB = kC; kC = kD; kD = tk;
    short* tv = vA; vA = vB; vB = vC; vC = vD; vD = tv;
  }

  lpart += __shfl_xor(lpart, 32, 64);

  if constexpr (V == 0) {
    const float invl = __builtin_amdgcn_rcpf(lpart);
    short* xr = xqT + ((size_t)bh * SQ_ + qidx) * 64;
    const float2* msvh = msv + h * DH_;
    for (int dt = 0; dt < 2; ++dt)
      for (int gg = 0; gg < 4; ++gg) {
        const int d0 = dt * 32 + gg * 8 + hi * 4;
        float qv[4];
        for (int r = 0; r < 4; ++r) qv[r] = qsrc[(size_t)(d0 + r) * SQ_];
        const float2 c0 = msvh[d0 + 0], c1 = msvh[d0 + 1],
                     c2v = msvh[d0 + 2], c3 = msvh[d0 + 3];
        short4 xv;
        xv.x = f2bf((qv[0] + oacc[dt][gg * 4 + 0] * invl) * c0.x - c0.y);
        xv.y = f2bf((qv[1] + oacc[dt][gg * 4 + 1] * invl) * c1.x - c1.y);
        xv.z = f2bf((qv[2] + oacc[dt][gg * 4 + 2] * invl) * c2v.x - c2v.y);
        xv.w = f2bf((qv[3] + oacc[dt][gg * 4 + 3] * invl) * c3.x - c3.y);
        *reinterpret_cast<short4*>(xr + d0) = xv;
      }
  } else {
    keepx16(oacc[0]);
    keepx16(oacc[1]);
    keepf(lpart);
  }
}

// proj (r12 shape, unchanged).
__global__ __launch_bounds__(256) void proj_kernel(
    const short* __restrict__ Wb, const short* __restrict__ xT,
    const float* __restrict__ bias, float* __restrict__ out)
{
  __shared__ short xs[64 * 512];
  const int q0 = blockIdx.x * 64;
  const int o0 = blockIdx.y * 256;
  const int b  = blockIdx.z;
  const int tid = threadIdx.x, w = tid >> 6, l = tid & 63;
  const int l15 = l & 15, g = l >> 4;

  const short* xb = xT + (size_t)b * (H_ * SQ_ * 64);
  for (int hh = w * 2; hh < w * 2 + 2; ++hh) {
    const short* src = xb + ((size_t)hh * SQ_ + q0) * 64;
    for (int j = 0; j < 8; ++j) {
      const short8 val = *reinterpret_cast<const short8*>(src + j * 512 + l * 8);
      const int row = j * 8 + (l >> 3);
      const int c16 = (hh * 8 + (l & 7)) ^ (row & 7);
      *reinterpret_cast<short8*>(&xs[row * 512 + c16 * 8]) = val;
    }
  }
  __syncthreads();

  floatx4 acc[4][4];
  for (int ai = 0; ai < 4; ++ai)
    for (int bj = 0; bj < 4; ++bj)
      acc[ai][bj] = floatx4{0.f, 0.f, 0.f, 0.f};

  const short* wbase = Wb + (size_t)(o0 + w * 64 + l15) * D_;

  for (int step = 0; step < 16; ++step) {
    short8 af[4];
    for (int ai = 0; ai < 4; ++ai)
      af[ai] = *reinterpret_cast<const short8*>(
          wbase + (size_t)(ai * 16) * D_ + step * 32 + g * 8);
    short8 bf[4];
    for (int bj = 0; bj < 4; ++bj) {
      const int row = bj * 16 + l15;
      const int c16 = (step * 4 + g) ^ (row & 7);
      bf[bj] = *reinterpret_cast<const short8*>(&xs[row * 512 + c16 * 8]);
    }
    for (int ai = 0; ai < 4; ++ai)
      for (int bj = 0; bj < 4; ++bj)
        acc[ai][bj] = __builtin_amdgcn_mfma_f32_16x16x32_bf16(af[ai], bf[bj],
                                                              acc[ai][bj], 0, 0, 0);
  }

  for (int ai = 0; ai < 4; ++ai)
    for (int r = 0; r < 4; ++r) {
      const int o = o0 + w * 64 + ai * 16 + g * 4 + r;
      const float bo = bias[o];
      float* orow = out + ((size_t)b * D_ + o) * SQ_ + q0;
      for (int bj = 0; bj < 4; ++bj) {
        const float val = acc[ai][bj][r] + bo;
        const float e = __builtin_amdgcn_exp2f(-val * LOG2E_);
        orow[bj * 16 + l15] = val * __builtin_amdgcn_rcpf(1.0f + e);
      }
    }
}

extern "C" void kernel_launch(void* const* d_in, const int* in_sizes, int n_in,
                              void* d_out, int out_size, void* d_ws, size_t ws_size,
                              hipStream_t stream) {
  const float*   q     = (const float*)d_in[0];
  const float*   k     = (const float*)d_in[1];
  const float*   v     = (const float*)d_in[2];
  const uint8_t* mask  = (const uint8_t*)d_in[3];
  const float*   gamma = (const float*)d_in[4];
  const float*   beta  = (const float*)d_in[5];
  const float*   m_qk  = (const float*)d_in[6];
  const float*   s_qk  = (const float*)d_in[7];
  const float*   m_v   = (const float*)d_in[8];
  const float*   s_v   = (const float*)d_in[9];
  const float*   W     = (const float*)d_in[10];
  const float*   bias  = (const float*)d_in[11];
  float* out = (float*)d_out;

  char* ws = (char*)d_ws;
  short*  Wb    = (short*)ws;
  short*  xqT   = (short*)(ws + (1u << 19));
  short*  kTb   = (short*)(ws + (1u << 19) + (1u << 24));
  short*  vbb   = (short*)(ws + (1u << 19) + 2u * (1u << 24));
  float2* msv   = (float2*)(ws + (1u << 19) + 3u * (1u << 24));
  int*    flag  = (int*)(ws + (1u << 19) + 3u * (1u << 24) + 4096);
  float*  kbias = (float*)(ws + (1u << 19) + 3u * (1u << 24) + 8192);

  detect_mask_kernel<<<1, 256, 0, stream>>>(mask, flag);
  megaprep_kernel<<<2337, 256, 0, stream>>>(k, v, kTb, vbb, mask, flag, kbias,
                                            m_v, s_v, msv, W, Wb);
  attn_t<0><<<512, 512, 0, stream>>>(q, xqT, kTb, vbb, gamma, beta,
                                     m_qk, s_qk, msv, kbias);
  // ---- ablation variants (no output writes; timing via per-dispatch rocprof) ----
  attn_t<1><<<512, 512, 0, stream>>>(q, xqT, kTb, vbb, gamma, beta,
                                     m_qk, s_qk, msv, kbias);
  attn_t<2><<<512, 512, 0, stream>>>(q, xqT, kTb, vbb, gamma, beta,
                                     m_qk, s_qk, msv, kbias);
  attn_t<3><<<512, 512, 0, stream>>>(q, xqT, kTb, vbb, gamma, beta,
                                     m_qk, s_qk, msv, kbias);
  attn_t<4><<<512, 512, 0, stream>>>(q, xqT, kTb, vbb, gamma, beta,
                                     m_qk, s_qk, msv, kbias);
  proj_kernel<<<dim3(8, 2, 32), 256, 0, stream>>>(Wb, xqT, bias, out);
}

// Round 15
// 96.437 us; speedup vs baseline: 1.8830x; 1.8830x over previous
//
#include <hip/hip_runtime.h>
#include <hip/hip_bf16.h>
#include <cstdint>
#include <cstddef>

typedef __attribute__((ext_vector_type(8))) short short8;
typedef __attribute__((ext_vector_type(4))) float floatx4;
typedef __attribute__((ext_vector_type(16))) float floatx16;

#define B_ 32
#define H_ 8
#define D_ 512
#define DH_ 64
#define SQ_ 512
#define SK_ 512
#define NEG_INF_ -1000000000.0f
#define LOG2E_ 1.4426950408889634f
#define FIXED_MAX_ 24.0f

__device__ __forceinline__ short f2bf(float f) {
  union { float f; uint32_t u; } x; x.f = f;
  uint32_t r = x.u + 0x7FFFu + ((x.u >> 16) & 1u);
  return (short)(r >> 16);
}
__device__ __forceinline__ uint32_t cvt_pk_bf16(float lo, float hi) {
  uint32_t r;
  asm("v_cvt_pk_bf16_f32 %0, %1, %2" : "=v"(r) : "v"(lo), "v"(hi));
  return r;
}
// Swap upper-half lanes of a with lower-half lanes of b (both modified).
__device__ __forceinline__ void plane32_swap(uint32_t& a, uint32_t& b) {
  asm("v_permlane32_swap_b32 %0, %1" : "+v"(a), "+v"(b));
}
__device__ __forceinline__ void gload16(const void* g, void* lds) {
  __builtin_amdgcn_global_load_lds(
      (const __attribute__((address_space(1))) void*)g,
      (__attribute__((address_space(3))) void*)lds, 16, 0, 0);
}

// Detect mask element layout: int32 (flag=0) vs byte/bool (flag=1).
__global__ void detect_mask_kernel(const uint8_t* __restrict__ m, int* __restrict__ flag) {
  __shared__ int found;
  if (threadIdx.x == 0) found = 0;
  __syncthreads();
  int any = 0;
  for (int i = threadIdx.x; i < B_ * SK_; i += 256) {
    if ((i & 3) != 0 && m[i] != 0) any = 1;
  }
  if (any) atomicOr(&found, 1);
  __syncthreads();
  if (threadIdx.x == 0) *flag = found;
}

// One fused prep launch (256 thr), role by blockIdx.x (same as r12).
__global__ __launch_bounds__(256) void megaprep_kernel(
    const float* __restrict__ ksrc, const float* __restrict__ vsrc,
    short* __restrict__ kdst, short* __restrict__ vdst,
    const uint8_t* __restrict__ mask8, const int* __restrict__ flag,
    float* __restrict__ kbias,
    const float* __restrict__ m_v, const float* __restrict__ s_v,
    float2* __restrict__ msv,
    const float* __restrict__ W, short* __restrict__ Wb)
{
  __shared__ short t[64][68];
  const int id = blockIdx.x, tid = threadIdx.x;

  if (id < 2048) {
    const int bx = id & 7, h = (id >> 3) & 7, b = id >> 6;
    const int s0 = bx * 64;
    {
      const size_t base = ((size_t)b * D_ + h * DH_ + bx * 8) * (size_t)SK_;
      const float4* vs = reinterpret_cast<const float4*>(vsrc + base);
      short4* vd = reinterpret_cast<short4*>(vdst + base);
      for (int j = 0; j < 4; ++j) {
        const int i = j * 256 + tid;
        const float4 f = vs[i];
        short4 s;
        s.x = f2bf(f.x); s.y = f2bf(f.y); s.z = f2bf(f.z); s.w = f2bf(f.w);
        vd[i] = s;
      }
    }
    const float* sp = ksrc + ((size_t)b * D_ + h * DH_) * (size_t)SK_ + s0;
    const int sg = (tid & 15) * 4;
    int dloc = tid >> 4;
    for (int it = 0; it < 4; ++it, dloc += 16) {
      const float4 f = *reinterpret_cast<const float4*>(sp + (size_t)dloc * SK_ + sg);
      t[sg + 0][dloc] = f2bf(f.x);
      t[sg + 1][dloc] = f2bf(f.y);
      t[sg + 2][dloc] = f2bf(f.z);
      t[sg + 3][dloc] = f2bf(f.w);
    }
    __syncthreads();
    short* dp = kdst + ((size_t)(b * H_ + h) * SQ_ + s0) * 64;
    for (int it = 0; it < 4; ++it) {
      const int c = tid + 256 * it;
      const int ss = c >> 4, pos = (c & 15) * 4;
      *reinterpret_cast<short4*>(dp + (size_t)ss * 64 + pos) =
          *reinterpret_cast<const short4*>(&t[ss][pos]);
    }
  } else if (id < 2080) {
    const int b = id - 2048;
    const int fl = *flag;
    for (int j = 0; j < 2; ++j) {
      const int kk = j * 256 + tid;
      int mv;
      if (fl) mv = mask8[b * SK_ + kk];
      else    mv = reinterpret_cast<const int*>(mask8)[b * SK_ + kk];
      kbias[b * SK_ + kk] = mv ? NEG_INF_ * LOG2E_ : 0.0f;
    }
  } else if (id == 2080) {
    for (int j = 0; j < 2; ++j) {
      const int d = j * 256 + tid;
      const float inv = 1.0f / s_v[d];
      msv[d] = make_float2(inv, m_v[d] * inv);
    }
  } else {
    const int i = (id - 2081) * 256 + tid;
    const float4 f = reinterpret_cast<const float4*>(W)[i];
    short4 s;
    s.x = f2bf(f.x); s.y = f2bf(f.y); s.z = f2bf(f.z); s.w = f2bf(f.w);
    reinterpret_cast<short4*>(Wb)[i] = s;
  }
}

// Swapped-operand 32x32 flash attention, fixed-max softmax (P = exp2(s-24)).
// ONE block per (b,h): 1024 threads / 16 waves, wave w owns q-rows [32w,32w+32).
// Grid 256 = 1 block/CU. ALL 8 64-col K/V tiles staged up front (r9's verified
// staging geometry: waves 0-7 stage K chunks, 8-15 stage V chunks; one gload16
// per wave per tile). ONE order-robust vmcnt(0) + ONE barrier; the compute loop
// has no waits and no barriers — LDS is immutable, waves fully de-phased.
__global__ __launch_bounds__(1024, 4) void attn_kernel(
    const float* __restrict__ qf32,     // [B][D][SQ] f32
    short* __restrict__ xqT,            // out x: [B][H][SQ][64] bf16
    const short* __restrict__ kT,       // [B][H][SK][64] bf16
    const short* __restrict__ vb,       // [B][D][SK] bf16
    const float* __restrict__ gamma, const float* __restrict__ beta,
    const float* __restrict__ m_qk, const float* __restrict__ s_qk,
    const float2* __restrict__ msv, const float* __restrict__ kbias)
{
  __shared__ float bias_s[SK_];
  __shared__ short kbuf[8][4096];       // per 64-tile: [64 k-rows][64 d shorts]
  __shared__ short vbuf[8][4096];       // per 64-tile: [64 d-rows][64 k shorts]

  const int bh = blockIdx.x;            // 0..255
  const int h = bh & 7, b = bh >> 3;

  const int tid = threadIdx.x, w = tid >> 6, l = tid & 63;
  const int l31 = l & 31, hi = l >> 5;
  const int swz = l31 & 7;

  const float gh = gamma[h], be = beta[h], mq = m_qk[h], sq = s_qk[h];
  const float a2 = gh / (sq * 8.0f) * LOG2E_;
  const float c2 = (be - mq * gh / sq) * LOG2E_ - FIXED_MAX_;

  const int qidx = w * 32 + l31;
  const short* kbase = kT + (size_t)bh * SK_ * 64;
  const short* vbase = vb + ((size_t)b * D_ + h * DH_) * (size_t)SK_;
  const float* qsrc = qf32 + ((size_t)b * D_ + h * DH_) * (size_t)SQ_ + qidx;

  // bias row to LDS (threads 0..127)
  if (tid < 128) {
    floatx4 t = reinterpret_cast<const floatx4*>(kbias + (size_t)b * SK_)[tid];
    t += c2;                             // fold affine offset + fixed max
    reinterpret_cast<floatx4*>(bias_s)[tid] = t;
  }

  // Q fragments (B-operand) direct from f32
  short8 qf[4];
  for (int st = 0; st < 4; ++st) {
    float fv[8];
    for (int j = 0; j < 8; ++j)
      fv[j] = qsrc[(size_t)(st * 16 + hi * 8 + j) * SQ_];
    union { uint32_t u[4]; short8 s; } qk;
    for (int j2 = 0; j2 < 4; ++j2)
      qk.u[j2] = cvt_pk_bf16(fv[2 * j2], fv[2 * j2 + 1]);
    qf[st] = qk.s;
  }

  // staging geometry (r9-verified): one 1KB chunk (8 rows x 128B) per wave
  // per tile; source pre-swizzled c16 ^= row&7 (G21/m173), LDS dest linear.
  const int rsub = l >> 3;              // row within chunk 0..7
  const int c16s = (l & 7) ^ rsub;      // swizzled 16B col in source
  const int ck = w & 7;                 // chunk index

#pragma unroll
  for (int t = 0; t < 8; ++t) {
    const int k0t = t * 64;
    if (w < 8)
      gload16(kbase + (size_t)(k0t + ck * 8 + rsub) * 64 + c16s * 8,
              &kbuf[t][ck * 512]);
    else
      gload16(vbase + (size_t)(ck * 8 + rsub) * SK_ + k0t + c16s * 8,
              &vbuf[t][ck * 512]);
  }

  floatx16 oacc[2];
  for (int i = 0; i < 16; ++i) { oacc[0][i] = 0.f; oacc[1][i] = 0.f; }
  float lpart = 0.f;

  // single order-robust sync: ALL staging (and bias) complete, then no more
  // barriers/waits anywhere — LDS immutable from here on.
  asm volatile("s_waitcnt vmcnt(0) lgkmcnt(0)" ::: "memory");
  __builtin_amdgcn_s_barrier();
  __builtin_amdgcn_sched_barrier(0);

#pragma unroll 1
  for (int it = 0; it < 8; ++it) {
    const int k0 = it * 64;
    const short* kl = kbuf[it];
    const short* vl = vbuf[it];

    // ---- S^T = K Q (fragments from swizzled LDS) ----
    floatx16 s0, s1;
    for (int i = 0; i < 16; ++i) { s0[i] = 0.f; s1[i] = 0.f; }
    __builtin_amdgcn_s_setprio(1);
    for (int st = 0; st < 4; ++st) {
      const short8 ka = *reinterpret_cast<const short8*>(
          &kl[(size_t)l31 * 64 + (((st << 1) | hi) ^ swz) * 8]);
      s0 = __builtin_amdgcn_mfma_f32_32x32x16_bf16(ka, qf[st], s0, 0, 0, 0);
    }
    for (int st = 0; st < 4; ++st) {
      const short8 kb = *reinterpret_cast<const short8*>(
          &kl[(size_t)(32 + l31) * 64 + (((st << 1) | hi) ^ swz) * 8]);
      s1 = __builtin_amdgcn_mfma_f32_32x32x16_bf16(kb, qf[st], s1, 0, 0, 0);
    }
    __builtin_amdgcn_s_setprio(0);

    // P = exp2(s*a2 + bias) — raw v_exp_f32; masked: exp2(-1.4e9) = 0 exactly
    float p2[32];
    for (int sub = 0; sub < 2; ++sub)
      for (int gg = 0; gg < 4; ++gg) {
        const floatx4 bv = *reinterpret_cast<const floatx4*>(
            &bias_s[k0 + sub * 32 + gg * 8 + hi * 4]);
        for (int r = 0; r < 4; ++r) {
          const float sc = sub ? s1[gg * 4 + r] : s0[gg * 4 + r];
          p2[sub * 16 + gg * 4 + r] =
              __builtin_amdgcn_exp2f(__builtin_fmaf(sc, a2, bv[r]));
        }
      }

    // partial row-sum (lane-local; cross-lane deferred to end)
    {
      float a16[16];
      for (int i = 0; i < 16; ++i) a16[i] = p2[i] + p2[i + 16];
      float a8[8];
      for (int i = 0; i < 8; ++i) a8[i] = a16[i] + a16[i + 8];
      lpart += ((a8[0] + a8[4]) + (a8[1] + a8[5])) + ((a8[2] + a8[6]) + (a8[3] + a8[7]));
    }

    // P -> bf16 words; word j holds (k=2j, k=2j+1) of this lane's k-set
    uint32_t Wd[16];
    for (int j = 0; j < 16; ++j) Wd[j] = cvt_pk_bf16(p2[2 * j], p2[2 * j + 1]);

    // PV: O^T[d][q] += V[d][k] * P[k][q]; cross-half exchange via permlane32_swap
    __builtin_amdgcn_s_setprio(1);
    for (int kc = 0; kc < 4; ++kc) {
      const int base = (kc >> 1) * 8 + (kc & 1) * 4;
      uint32_t x0 = Wd[base + 0], x1 = Wd[base + 1];
      uint32_t y0 = Wd[base + 2], y1 = Wd[base + 3];
      plane32_swap(x0, y0);
      plane32_swap(x1, y1);
      union { uint32_t u[4]; short8 s; } pk;
      pk.u[0] = x0; pk.u[1] = x1; pk.u[2] = y0; pk.u[3] = y1;
      const short8 pb = pk.s;
      const short8 va0 = *reinterpret_cast<const short8*>(
          &vl[(size_t)l31 * 64 + (((kc << 1) | hi) ^ swz) * 8]);
      const short8 va1 = *reinterpret_cast<const short8*>(
          &vl[(size_t)(32 + l31) * 64 + (((kc << 1) | hi) ^ swz) * 8]);
      oacc[0] = __builtin_amdgcn_mfma_f32_32x32x16_bf16(va0, pb, oacc[0], 0, 0, 0);
      oacc[1] = __builtin_amdgcn_mfma_f32_32x32x16_bf16(va1, pb, oacc[1], 0, 0, 0);
    }
    __builtin_amdgcn_s_setprio(0);
  }

  lpart += __shfl_xor(lpart, 32, 64);    // complete row sum

  // ---- epilogue: x = (q + O/l)*inv_s - m*inv_s; residual q re-read f32 (L2-hot) ----
  const float invl = __builtin_amdgcn_rcpf(lpart);
  short* xr = xqT + ((size_t)bh * SQ_ + qidx) * 64;
  const float2* msvh = msv + h * DH_;
  for (int dt = 0; dt < 2; ++dt)
    for (int gg = 0; gg < 4; ++gg) {
      const int d0 = dt * 32 + gg * 8 + hi * 4;
      float qv[4];
      for (int r = 0; r < 4; ++r) qv[r] = qsrc[(size_t)(d0 + r) * SQ_];
      const float2 c0 = msvh[d0 + 0], c1 = msvh[d0 + 1],
                   c2v = msvh[d0 + 2], c3 = msvh[d0 + 3];
      short4 xv;
      xv.x = f2bf((qv[0] + oacc[dt][gg * 4 + 0] * invl) * c0.x - c0.y);
      xv.y = f2bf((qv[1] + oacc[dt][gg * 4 + 1] * invl) * c1.x - c1.y);
      xv.z = f2bf((qv[2] + oacc[dt][gg * 4 + 2] * invl) * c2v.x - c2v.y);
      xv.w = f2bf((qv[3] + oacc[dt][gg * 4 + 3] * invl) * c3.x - c3.y);
      *reinterpret_cast<short4*>(xr + d0) = xv;
    }
}

// proj (r12 shape, unchanged).
__global__ __launch_bounds__(256) void proj_kernel(
    const short* __restrict__ Wb, const short* __restrict__ xT,
    const float* __restrict__ bias, float* __restrict__ out)
{
  __shared__ short xs[64 * 512];
  const int q0 = blockIdx.x * 64;
  const int o0 = blockIdx.y * 256;
  const int b  = blockIdx.z;
  const int tid = threadIdx.x, w = tid >> 6, l = tid & 63;
  const int l15 = l & 15, g = l >> 4;

  const short* xb = xT + (size_t)b * (H_ * SQ_ * 64);
  for (int hh = w * 2; hh < w * 2 + 2; ++hh) {
    const short* src = xb + ((size_t)hh * SQ_ + q0) * 64;
    for (int j = 0; j < 8; ++j) {
      const short8 val = *reinterpret_cast<const short8*>(src + j * 512 + l * 8);
      const int row = j * 8 + (l >> 3);
      const int c16 = (hh * 8 + (l & 7)) ^ (row & 7);
      *reinterpret_cast<short8*>(&xs[row * 512 + c16 * 8]) = val;
    }
  }
  __syncthreads();

  floatx4 acc[4][4];
  for (int ai = 0; ai < 4; ++ai)
    for (int bj = 0; bj < 4; ++bj)
      acc[ai][bj] = floatx4{0.f, 0.f, 0.f, 0.f};

  const short* wbase = Wb + (size_t)(o0 + w * 64 + l15) * D_;

  for (int step = 0; step < 16; ++step) {
    short8 af[4];
    for (int ai = 0; ai < 4; ++ai)
      af[ai] = *reinterpret_cast<const short8*>(
          wbase + (size_t)(ai * 16) * D_ + step * 32 + g * 8);
    short8 bf[4];
    for (int bj = 0; bj < 4; ++bj) {
      const int row = bj * 16 + l15;
      const int c16 = (step * 4 + g) ^ (row & 7);
      bf[bj] = *reinterpret_cast<const short8*>(&xs[row * 512 + c16 * 8]);
    }
    for (int ai = 0; ai < 4; ++ai)
      for (int bj = 0; bj < 4; ++bj)
        acc[ai][bj] = __builtin_amdgcn_mfma_f32_16x16x32_bf16(af[ai], bf[bj],
                                                              acc[ai][bj], 0, 0, 0);
  }

  for (int ai = 0; ai < 4; ++ai)
    for (int r = 0; r < 4; ++r) {
      const int o = o0 + w * 64 + ai * 16 + g * 4 + r;
      const float bo = bias[o];
      float* orow = out + ((size_t)b * D_ + o) * SQ_ + q0;
      for (int bj = 0; bj < 4; ++bj) {
        const float val = acc[ai][bj][r] + bo;
        const float e = __builtin_amdgcn_exp2f(-val * LOG2E_);
        orow[bj * 16 + l15] = val * __builtin_amdgcn_rcpf(1.0f + e);
      }
    }
}

extern "C" void kernel_launch(void* const* d_in, const int* in_sizes, int n_in,
                              void* d_out, int out_size, void* d_ws, size_t ws_size,
                              hipStream_t stream) {
  const float*   q     = (const float*)d_in[0];
  const float*   k     = (const float*)d_in[1];
  const float*   v     = (const float*)d_in[2];
  const uint8_t* mask  = (const uint8_t*)d_in[3];
  const float*   gamma = (const float*)d_in[4];
  const float*   beta  = (const float*)d_in[5];
  const float*   m_qk  = (const float*)d_in[6];
  const float*   s_qk  = (const float*)d_in[7];
  const float*   m_v   = (const float*)d_in[8];
  const float*   s_v   = (const float*)d_in[9];
  const float*   W     = (const float*)d_in[10];
  const float*   bias  = (const float*)d_in[11];
  float* out = (float*)d_out;

  char* ws = (char*)d_ws;
  short*  Wb    = (short*)ws;                                   // 512 KB
  short*  xqT   = (short*)(ws + (1u << 19));                    // 16 MB (x output)
  short*  kTb   = (short*)(ws + (1u << 19) + (1u << 24));       // 16 MB
  short*  vbb   = (short*)(ws + (1u << 19) + 2u * (1u << 24));  // 16 MB
  float2* msv   = (float2*)(ws + (1u << 19) + 3u * (1u << 24)); // 4 KB
  int*    flag  = (int*)(ws + (1u << 19) + 3u * (1u << 24) + 4096);
  float*  kbias = (float*)(ws + (1u << 19) + 3u * (1u << 24) + 8192); // 64 KB

  detect_mask_kernel<<<1, 256, 0, stream>>>(mask, flag);
  megaprep_kernel<<<2337, 256, 0, stream>>>(k, v, kTb, vbb, mask, flag, kbias,
                                            m_v, s_v, msv, W, Wb);
  attn_kernel<<<256, 1024, 0, stream>>>(q, xqT, kTb, vbb, gamma, beta,
                                        m_qk, s_qk, msv, kbias);
  proj_kernel<<<dim3(8, 2, 32), 256, 0, stream>>>(Wb, xqT, bias, out);
}